// Round 5
// baseline (2100.957 us; speedup 1.0000x reference)
//
#include <hip/hip_runtime.h>
#include <hip/hip_bf16.h>
#include <stdint.h>

#define B_ 64
#define T_ 512
#define I_ 1024
#define H_ 1024
#define BH (B_*H_)

typedef __attribute__((ext_vector_type(8))) short short8;
typedef __attribute__((ext_vector_type(4))) float f32x4;
typedef __attribute__((ext_vector_type(4))) unsigned u32x4;
typedef __attribute__((ext_vector_type(2))) unsigned u32x2;

static __device__ __forceinline__ unsigned short f2bf(float f) {
  union { float f; unsigned u; } v; v.f = f;
  unsigned r = v.u + 0x7fffu + ((v.u >> 16) & 1u);
  return (unsigned short)(r >> 16);
}

static __device__ __forceinline__ void glds16(const void* g, void* l) {
  __builtin_amdgcn_global_load_lds(
      (const __attribute__((address_space(1))) unsigned int*)g,
      (__attribute__((address_space(3))) unsigned int*)l, 16, 0, 0);
}

// ---------------- weight conversion f32 -> bf16 ----------------
__global__ void convert_weights(const f32x4* __restrict__ wih, const f32x4* __restrict__ whh,
                                uint2* __restrict__ wih_b, uint2* __restrict__ whh_b)
{
  int idx = blockIdx.x * blockDim.x + threadIdx.x;
  f32x4 a = wih[idx];
  uint2 o;
  o.x = f2bf(a[0]) | ((unsigned)f2bf(a[1]) << 16);
  o.y = f2bf(a[2]) | ((unsigned)f2bf(a[3]) << 16);
  wih_b[idx] = o;
  f32x4 b = whh[idx];
  uint2 p;
  p.x = f2bf(b[0]) | ((unsigned)f2bf(b[1]) << 16);
  p.y = f2bf(b[2]) | ((unsigned)f2bf(b[3]) << 16);
  whh_b[idx] = p;
}

// ---------------- x_proj GEMM (unchanged) ----------------
__launch_bounds__(256)
__global__ void gemm_xproj(const float* __restrict__ in,
                           const unsigned short* __restrict__ wb,
                           const float* __restrict__ bih,
                           const float* __restrict__ bhh,
                           float* __restrict__ out)
{
  __shared__ __align__(16) unsigned char As[16384];
  __shared__ __align__(16) unsigned char Bs[16384];
  const int tid = threadIdx.x;
  const int lane = tid & 63;
  const int w = tid >> 6;
  const int wm = w >> 1, wn = w & 1;
  const int bn = blockIdx.x, bm = blockIdx.y;

  const int ar = tid >> 1;
  const int ah = tid & 1;
  const int R0 = bm*128 + ar;
  const float* asrc = in + (size_t)(R0 & 63) * (T_*I_) + (size_t)(R0 >> 6) * I_ + ah*32;
  unsigned char* adst_base = As + ar*128;
  const int aswz_w = (ar & 7) << 4;

  f32x4 acc[4][4];
  #pragma unroll
  for (int i = 0; i < 4; ++i)
    #pragma unroll
    for (int j = 0; j < 4; ++j)
      acc[i][j] = (f32x4){0.f,0.f,0.f,0.f};

  f32x4 av[8];
  #pragma unroll
  for (int j = 0; j < 8; ++j) av[j] = *(const f32x4*)(asrc + 0*64 + j*4);

  for (int kt = 0; kt < 16; ++kt) {
    __syncthreads();
    #pragma unroll
    for (int q = 0; q < 4; ++q) {
      int inst = w*4 + q;
      int rb = inst*8 + (lane >> 3);
      int srcoff = ((bn*128 + rb) * I_ + kt*64) * 2 + (((lane & 7) * 16) ^ ((rb & 7) << 4));
      glds16((const unsigned char*)wb + srcoff, Bs + inst*1024);
    }
    #pragma unroll
    for (int j2 = 0; j2 < 4; ++j2) {
      uint4 val;
      f32x4 v0 = av[j2*2], v1 = av[j2*2+1];
      val.x = f2bf(v0[0]) | ((unsigned)f2bf(v0[1]) << 16);
      val.y = f2bf(v0[2]) | ((unsigned)f2bf(v0[3]) << 16);
      val.z = f2bf(v1[0]) | ((unsigned)f2bf(v1[1]) << 16);
      val.w = f2bf(v1[2]) | ((unsigned)f2bf(v1[3]) << 16);
      int koffb = ah*64 + j2*16;
      *(uint4*)(adst_base + (koffb ^ aswz_w)) = val;
    }
    __syncthreads();
    if (kt < 15) {
      #pragma unroll
      for (int j = 0; j < 8; ++j) av[j] = *(const f32x4*)(asrc + (kt+1)*64 + j*4);
    }
    #pragma unroll
    for (int kb = 0; kb < 2; ++kb) {
      const int kby = kb*64 + ((lane >> 4) << 4);
      short8 af[4], bfr[4];
      #pragma unroll
      for (int i = 0; i < 4; ++i) {
        int ra = wm*64 + i*16 + (lane & 15);
        af[i] = *(const short8*)(As + ra*128 + (kby ^ ((ra & 7) << 4)));
      }
      #pragma unroll
      for (int j = 0; j < 4; ++j) {
        int rb2 = wn*64 + j*16 + (lane & 15);
        bfr[j] = *(const short8*)(Bs + rb2*128 + (kby ^ ((rb2 & 7) << 4)));
      }
      #pragma unroll
      for (int i = 0; i < 4; ++i)
        #pragma unroll
        for (int j = 0; j < 4; ++j)
          acc[i][j] = __builtin_amdgcn_mfma_f32_16x16x32_bf16(af[i], bfr[j], acc[i][j], 0, 0, 0);
    }
  }
  #pragma unroll
  for (int j = 0; j < 4; ++j) {
    int col = bn*128 + wn*64 + j*16 + (lane & 15);
    float bias = bih[col] + bhh[col];
    #pragma unroll
    for (int i = 0; i < 4; ++i) {
      int Rb = bm*128 + wm*64 + i*16 + ((lane >> 4) << 2);
      #pragma unroll
      for (int q = 0; q < 4; ++q) {
        int R = Rb + q;
        out[(size_t)(R >> 6) * BH + (size_t)(R & 63) * H_ + col] = acc[i][j][q] + bias;
      }
    }
  }
}

// ---------------- recurrence: wave-tag release, untagged coalesced payload ----------------
// 64 WGs: gb=g>>4 (16 batch rows), gn=g&15 (64 H cols).
// Payload: hx[parity 2][gb 4][slice 16][2KB]; slot s = row*16 + col4 (8B = 4 bf16).
// Tags:    hx+262144 + (parity*4+gb)*256 + slice*16 + wave*4  (value = step t).
// Producer: payload stores -> vmcnt(0) -> lane0 wave-tag store (agent scope, sc1).
// Consumer wave w: poll its 4 slices' 16 tags (256B region) -> one coalesced 8KB
// payload fetch -> swizzled LDS stage. Uniform: own slice goes through global too.
__launch_bounds__(256, 1)
__global__ void rnn_recur(const unsigned short* __restrict__ whh_b,
                          float* __restrict__ out,
                          unsigned char* __restrict__ hx)
{
  extern __shared__ __align__(16) unsigned char lds[];
  const int tid = threadIdx.x;
  const int lane = tid & 63;
  const int w = tid >> 6;
  const int g = blockIdx.x;
  const int gb = g >> 4;
  const int gn = g & 15;

  // ---- one-time W_hh slice: global -> LDS (swizzled) -> registers ----
  for (int q = 0; q < 32; ++q) {
    int inst = w*32 + q;
    int nl = inst >> 1;
    int koff = (inst & 1)*1024 + lane*16;
    size_t srcoff = (size_t)(gn*64 + nl)*2048 + (size_t)(koff ^ ((nl & 7) << 4));
    glds16((const unsigned char*)whh_b + srcoff, lds + inst*1024);
  }
  asm volatile("s_waitcnt vmcnt(0)" ::: "memory");
  __syncthreads();

  const int arow = w*16 + (lane & 15);
  const unsigned char* wsrow = lds + (size_t)arow*2048;
  const int aswz = (arow & 7) << 4;
  const int klane = (lane >> 4) << 4;
  short8 af[32];
  #pragma unroll
  for (int kb = 0; kb < 32; ++kb)
    af[kb] = *(const short8*)(wsrow + ((kb*64 + klane) ^ aswz));
  __syncthreads();   // W region reused as hs double-buffer below

  const int bb = lane & 15;
  const int nq = (lane >> 4) << 2;
  const int colb = gn*64 + w*16 + nq;
  const int brow = gb*16 + bb;
  const int bswz = (bb & 7) << 4;

  // stage-side roles (per-lane, per-wave slices w, w+4, w+8, w+12)
  const int srr = lane >> 2;                 // staged row 0..15
  const unsigned sws = (unsigned)((srr & 7) << 4);
  const int scb = (lane & 3) * 32;           // 32B col-chunk within slice

  // tag poll role: lane i checks tag[slice w+4*(i>>2)][wave i&3]
  const int ti = lane & 15;
  const int psj = w + ((ti >> 2) << 2);
  const int ptw = ti & 3;

  f32x4 xp = *(const f32x4*)(out + (size_t)brow*H_ + colb);

  for (int t = 0; t < T_; ++t) {
    unsigned char* hsb = lds + (size_t)(t & 1)*32768;
    unsigned char* hrow = hsb + (size_t)srr*2048;
    if (t == 0) {
      u32x4 Z = (u32x4){0u,0u,0u,0u};
      #pragma unroll
      for (int si = 0; si < 4; ++si) {
        int c0 = (w + 4*si)*128 + scb;
        *(u32x4*)(hrow + ((unsigned)c0 ^ sws)) = Z;
        *(u32x4*)(hrow + ((unsigned)(c0 + 16) ^ sws)) = Z;
      }
    } else {
      const unsigned want = (unsigned)t;
      // ---- poll wave tags (256B control region) ----
      const unsigned char* ta = hx + 262144 + (size_t)((t & 1)*4 + gb)*256 + psj*16 + ptw*4;
      for (;;) {
        unsigned tg;
        asm volatile("global_load_dword %0, %1, off sc1\n\ts_waitcnt vmcnt(0)"
                     : "=v"(tg) : "v"(ta) : "memory");
        if (__ballot(tg == want) == ~0ull) break;
        __builtin_amdgcn_s_sleep(1);
      }
      // ---- one coalesced payload fetch: 4 slices x 32B per lane ----
      const unsigned char* pb = hx + (size_t)(t & 1)*131072 + (size_t)gb*32768;
      u32x4 A0,B0,A1,B1,A2,B2,A3,B3;
      #define LD2(AA,BB,si) { const unsigned char* p = pb + (size_t)(w + 4*(si))*2048 + (size_t)lane*32; \
        asm volatile("global_load_dwordx4 %0, %2, off sc1\n\t" \
                     "global_load_dwordx4 %1, %2, off offset:16 sc1" \
                     : "=&v"(AA), "=&v"(BB) : "v"(p) : "memory"); }
      LD2(A0,B0,0) LD2(A1,B1,1) LD2(A2,B2,2) LD2(A3,B3,3)
      #undef LD2
      asm volatile("s_waitcnt vmcnt(0)"
        : "+v"(A0),"+v"(B0),"+v"(A1),"+v"(B1),"+v"(A2),"+v"(B2),"+v"(A3),"+v"(B3)
        :: "memory");
      // ---- stage to swizzled LDS tile ----
      #define STW(AA,BB,si) { int c0 = (w + 4*(si))*128 + scb; \
        *(u32x4*)(hrow + ((unsigned)c0 ^ sws)) = AA; \
        *(u32x4*)(hrow + ((unsigned)(c0 + 16) ^ sws)) = BB; }
      STW(A0,B0,0) STW(A1,B1,1) STW(A2,B2,2) STW(A3,B3,3)
      #undef STW
    }
    asm volatile("s_waitcnt lgkmcnt(0)\n\ts_barrier" ::: "memory");

    // ---- compute 64 cols x 16 rows, K=1024 ----
    const unsigned char* hfrow = hsb + (size_t)bb*2048;
    f32x4 acc0 = (f32x4){0.f,0.f,0.f,0.f}, acc1 = (f32x4){0.f,0.f,0.f,0.f};
    #pragma unroll
    for (int kb = 0; kb < 32; kb += 2) {
      short8 b0 = *(const short8*)(hfrow + ((kb*64 + klane) ^ bswz));
      short8 b1 = *(const short8*)(hfrow + (((kb+1)*64 + klane) ^ bswz));
      acc0 = __builtin_amdgcn_mfma_f32_16x16x32_bf16(af[kb],   b0, acc0, 0, 0, 0);
      acc1 = __builtin_amdgcn_mfma_f32_16x16x32_bf16(af[kb+1], b1, acc1, 0, 0, 0);
    }
    f32x4 hval;
    #pragma unroll
    for (int q = 0; q < 4; ++q)
      hval[q] = tanhf(acc0[q] + acc1[q] + xp[q]);

    // ---- release: payload stores -> drain -> wave tag ----
    if (t < T_-1) {
      u32x2 pay;
      pay[0] = f2bf(hval[0]) | ((unsigned)f2bf(hval[1]) << 16);
      pay[1] = f2bf(hval[2]) | ((unsigned)f2bf(hval[3]) << 16);
      const unsigned char* wp = hx + (size_t)((t+1) & 1)*131072 + (size_t)gb*32768
                                + (size_t)gn*2048 + (size_t)(bb*16 + w*4 + (lane >> 4))*8;
      asm volatile("global_store_dwordx2 %0, %1, off sc1" :: "v"(wp), "v"(pay) : "memory");
      asm volatile("s_waitcnt vmcnt(0)" ::: "memory");
      if (lane == 0) {
        const unsigned char* tw = hx + 262144 + (size_t)(((t+1) & 1)*4 + gb)*256 + gn*16 + w*4;
        unsigned tv = (unsigned)(t + 1);
        asm volatile("global_store_dword %0, %1, off sc1" :: "v"(tw), "v"(tv) : "memory");
      }
    }

    // ---- f32 outputs + next xp prefetch (off the handshake path) ----
    *(f32x4*)(out + (size_t)t*BH + (size_t)brow*H_ + colb) = hval;
    if (t == T_-1)
      *(f32x4*)(out + (size_t)T_*BH + (size_t)brow*H_ + colb) = hval;
    int tn = (t < T_-1) ? t+1 : t;
    xp = *(const f32x4*)(out + (size_t)tn*BH + (size_t)brow*H_ + colb);
  }
}

extern "C" void kernel_launch(void* const* d_in, const int* in_sizes, int n_in,
                              void* d_out, int out_size, void* d_ws, size_t ws_size,
                              hipStream_t stream)
{
  const float* in  = (const float*)d_in[0];
  const float* wih = (const float*)d_in[1];
  const float* whh = (const float*)d_in[2];
  const float* bih = (const float*)d_in[3];
  const float* bhh = (const float*)d_in[4];
  float* out = (float*)d_out;
  unsigned char* ws = (unsigned char*)d_ws;

  unsigned char*  hx    = ws;                                   // payload 256KB + tags 2KB
  unsigned short* wih_b = (unsigned short*)(ws + 524288);       // 2MB
  unsigned short* whh_b = (unsigned short*)(ws + 524288 + 2097152); // 2MB

  hipMemsetAsync(hx + 262144, 0, 4096, stream);   // clear tag region (graph-replay safe)
  convert_weights<<<1024, 256, 0, stream>>>((const f32x4*)wih, (const f32x4*)whh,
                                            (uint2*)wih_b, (uint2*)whh_b);
  gemm_xproj<<<dim3(8, 256), 256, 0, stream>>>(in, wih_b, bih, bhh, out);
  rnn_recur<<<64, 256, 131072, stream>>>(whh_b, out, hx);
}